// Round 1
// baseline (53.153 us; speedup 1.0000x reference)
//
#include <hip/hip_runtime.h>

#define C_IN   8
#define CH     8
#define Hh     128
#define Ww     192
#define HW     (Hh*Ww)
#define NINST  128
#define NPAR   169
#define STRIDE 8
#define OH     256
#define OW     384
#define OW2    (OW/2)

// Param layout per instance (169 floats):
// w0: [0,80)   (8 x 10, row-major: w0[o][i] = p[o*10+i])
// w1: [80,144) (8 x 8)
// w2: [144,152) (1 x 8)
// b0: [152,160), b1: [160,168), b2: [168]

__global__ __launch_bounds__(256, 2)
void mlp_kernel(const float* __restrict__ feats,
                const float* __restrict__ params,
                const float* __restrict__ locs,
                const int* __restrict__ im_inds,
                const int* __restrict__ fpn,
                float* __restrict__ logits)
{
    const int inst  = blockIdx.x;
    const int chunk = blockIdx.y;   // 12 chunks of 2048 px
    const int tid   = threadIdx.x;

    // wave-uniform param load (compiler can scalarize)
    const float* P = params + inst * NPAR;
    float w[NPAR];
    #pragma unroll
    for (int j = 0; j < NPAR; ++j) w[j] = P[j];

    const float ix = locs[inst*2 + 0];
    const float iy = locs[inst*2 + 1];
    const int   lvl = fpn[inst];
    const float inv_soi = 1.0f / (float)(64 << lvl);   // SOI = 64*2^lvl
    const float* fbase = feats + (size_t)im_inds[inst] * (C_IN * HW);
    float* outp = logits + (size_t)inst * HW;

    int p = chunk * 2048 + tid;
    #pragma unroll 1
    for (int it = 0; it < 8; ++it, p += 256) {
        const int h  = p / Ww;
        const int wq = p - h * Ww;
        const float rx = (ix - (float)(wq * STRIDE + STRIDE/2)) * inv_soi;
        const float ry = (iy - (float)(h  * STRIDE + STRIDE/2)) * inv_soi;

        float f[C_IN];
        #pragma unroll
        for (int c = 0; c < C_IN; ++c) f[c] = fbase[c * HW + p];

        float h1[CH];
        #pragma unroll
        for (int o = 0; o < CH; ++o) {
            float a = w[152 + o];
            a = fmaf(w[o*10 + 0], rx, a);
            a = fmaf(w[o*10 + 1], ry, a);
            #pragma unroll
            for (int c = 0; c < C_IN; ++c) a = fmaf(w[o*10 + 2 + c], f[c], a);
            h1[o] = fmaxf(a, 0.0f);
        }
        float h2[CH];
        #pragma unroll
        for (int o = 0; o < CH; ++o) {
            float a = w[160 + o];
            #pragma unroll
            for (int c = 0; c < CH; ++c) a = fmaf(w[80 + o*8 + c], h1[c], a);
            h2[o] = fmaxf(a, 0.0f);
        }
        float z = w[168];
        #pragma unroll
        for (int c = 0; c < CH; ++c) z = fmaf(w[144 + c], h2[c], z);

        outp[p] = z;
    }
}

// out[oy][ox] = u[max(oy-1,0)][max(ox-1,0)], u = 2x bilinear of logits with
// edge pad (row/col 128/192 == 127/191). For float2 at col pair (2m, 2m+1):
//   rm(x) = (1-fy)*L[y0][x] + fy*L[y1][x]
//   out[2m]   = 0.5*(rm(m-1)+rm(m))  (m=0 degenerates to rm(0))
//   out[2m+1] = rm(m)
__global__ __launch_bounds__(256)
void upsample_kernel(const float* __restrict__ logits, float2* __restrict__ out)
{
    const int idx = blockIdx.x * 256 + threadIdx.x;       // float2 index
    const int inst = idx / (OH * OW2);
    const int rem  = idx - inst * (OH * OW2);
    const int oy   = rem / OW2;
    const int m    = rem - oy * OW2;

    const float* L = logits + (size_t)inst * HW;

    const int ay = (oy > 0) ? oy - 1 : 0;
    const int y0 = ay >> 1;
    const int y1 = min(y0 + 1, Hh - 1);
    const float fy = (ay & 1) ? 0.5f : 0.0f;

    const int xm1 = (m > 0) ? m - 1 : 0;
    const float t00 = L[y0 * Ww + xm1];
    const float t01 = L[y0 * Ww + m];
    const float t10 = L[y1 * Ww + xm1];
    const float t11 = L[y1 * Ww + m];

    const float rma = fmaf(fy, t10 - t00, t00);
    const float rmb = fmaf(fy, t11 - t01, t01);

    float2 v;
    v.x = 0.5f * (rma + rmb);
    v.y = rmb;
    out[idx] = v;
}

extern "C" void kernel_launch(void* const* d_in, const int* in_sizes, int n_in,
                              void* d_out, int out_size, void* d_ws, size_t ws_size,
                              hipStream_t stream) {
    const float* feats  = (const float*)d_in[0];
    const float* params = (const float*)d_in[1];
    const float* locs   = (const float*)d_in[2];
    const int*   im     = (const int*)d_in[3];
    const int*   fpn    = (const int*)d_in[4];
    float*  out    = (float*)d_out;
    float*  logits = (float*)d_ws;   // 128*24576*4 = 12.58 MB

    dim3 g1(NINST, 12);
    mlp_kernel<<<g1, 256, 0, stream>>>(feats, params, locs, im, fpn, logits);

    const int n2 = NINST * OH * OW2;          // 6,291,456 float2
    upsample_kernel<<<n2 / 256, 256, 0, stream>>>(logits, (float2*)out);
}